// Round 4
// baseline (44598.975 us; speedup 1.0000x reference)
//
#include <hip/hip_runtime.h>

// RNN scan: h_t = tanh(h_{t-1} @ W + x_t @ V + b + b2), 512 steps.
// Round-4 redesign: the backend refuses >64-VGPR allocations for this
// kernel (rounds 2-3: amdgpu_waves_per_eu(4,4) + asm pins -> still
// VGPR_Count=64, 51 GB of scratch-spill FETCH traffic). So fit 64 VGPRs:
//   512 wgs x 1024 threads, exactly 2 wgs/CU (32 waves = CU cap, forced
//   packing -> all 256 CUs busy; rounds 1-3 likely ran on 128 CUs,
//   OccupancyPercent ~48%).
//   - group g = blockIdx.x>>5 owns batches [4g, 4g+4)   (16 groups)
//   - chunk c = blockIdx.x&31 owns columns [32c, 32c+32) (32 chunks)
//   - lane: col = lane&31, kh = lane>>5; slot = w*2+kh (32 k-slices)
//   - Wreg[32]: W[slot*32 .. +32][jcol]; Vreg[8]: V[slot*8 .. +8][jcol]
//   => ~41 persistent regs + temps fits the 64-VGPR budget: no spill.
// h is exchanged through d_out (chunk t of h_seq IS h_t) with agent-scope
// atomics; 32-wg groups sync via a monotonic counter barrier in d_ws.

#define SEQ    512
#define BATCH  64
#define INSZ   256
#define HID    1024
#define BPG    4     // batches per group
#define NSLOT  32    // k-slices (16 waves x 2 half-waves)
#define OUT_SEQ (SEQ * BATCH * HID)

__device__ __forceinline__ float ld_agent(const float* p) {
    return __hip_atomic_load(p, __ATOMIC_RELAXED, __HIP_MEMORY_SCOPE_AGENT);
}
__device__ __forceinline__ void st_agent(float* p, float v) {
    __hip_atomic_store(p, v, __ATOMIC_RELAXED, __HIP_MEMORY_SCOPE_AGENT);
}

__global__ void
__attribute__((amdgpu_flat_work_group_size(1024, 1024),
               amdgpu_waves_per_eu(8, 8)))
rnn_scan_kernel(
    const float* __restrict__ x,   // (SEQ, BATCH, INSZ)
    const float* __restrict__ V,   // (INSZ, HID)
    const float* __restrict__ W,   // (HID, HID)
    const float* __restrict__ b1,  // (HID,)
    const float* __restrict__ b2,  // (HID,)
    float* __restrict__ out,       // h_seq (SEQ*BATCH*HID) then h_last
    unsigned int* __restrict__ cnt)
{
    const int tid  = threadIdx.x;
    const int w    = tid >> 6;          // wave 0..15
    const int lane = tid & 63;
    const int col  = lane & 31;         // column within chunk
    const int kh   = lane >> 5;         // half-wave k split
    const int slot = w * 2 + kh;        // k-slice 0..31
    const int g    = blockIdx.x >> 5;   // batch group 0..15
    const int c    = blockIdx.x & 31;   // column chunk 0..31
    const int jcol = c * 32 + col;      // this lane's output column

    __shared__ __align__(16) float h_lds[BPG][HID];          // 16 KB
    __shared__ __align__(16) float pacc[BPG][32][NSLOT + 1]; // ~16.9 KB, 2-way banks

    // ---- persistent register-resident W and V fragments (one-time load) ----
    float Wreg[32];
#pragma unroll
    for (int i = 0; i < 32; ++i)
        Wreg[i] = W[(size_t)(slot * 32 + i) * HID + jcol];
    float Vreg[8];
#pragma unroll
    for (int i = 0; i < 8; ++i)
        Vreg[i] = V[(size_t)(slot * 8 + i) * HID + jcol];

    // Pin: prevent rematerialization of the loads inside the t-loop.
#pragma unroll
    for (int i = 0; i < 32; ++i) asm volatile("" : "+v"(Wreg[i]));
#pragma unroll
    for (int i = 0; i < 8; ++i)  asm volatile("" : "+v"(Vreg[i]));

    const float bias = b1[jcol] + b2[jcol];
    unsigned int* mycnt = cnt + g * 16;   // 64B-padded per-group counter

    // loop-invariant bases
    const float* xg = x + (size_t)g * BPG * INSZ + slot * 8;
    const float* hg = out + (size_t)g * BPG * HID;

    for (int t = 0; t < SEQ; ++t) {
        // ---- stage previous h (coherent: written by other CUs) ----
        if (t > 0) {
            const float* hprev = hg + (size_t)(t - 1) * (BATCH * HID);
#pragma unroll
            for (int i = 0; i < BPG; ++i)
                h_lds[i][tid] = ld_agent(hprev + i * HID + tid);
        }
        __syncthreads();

        float acc[BPG] = {0.f, 0.f, 0.f, 0.f};

        // ---- x_t @ V contribution (k-slice slot*8 .. +8) ----
        {
            const float* xt = xg + (size_t)t * (BATCH * INSZ);
#pragma unroll
            for (int b = 0; b < BPG; ++b) {
#pragma unroll
                for (int q = 0; q < 2; ++q) {
                    const float4 xa =
                        *reinterpret_cast<const float4*>(xt + b * INSZ + 4 * q);
                    acc[b] += xa.x * Vreg[4 * q + 0];
                    acc[b] += xa.y * Vreg[4 * q + 1];
                    acc[b] += xa.z * Vreg[4 * q + 2];
                    acc[b] += xa.w * Vreg[4 * q + 3];
                }
            }
        }

        // ---- h_{t-1} @ W contribution (k-slice slot*32 .. +32) ----
        if (t > 0) {
#pragma unroll
            for (int b = 0; b < BPG; ++b) {
                const float* hrow = &h_lds[b][slot * 32]; // half-wave-uniform
#pragma unroll
                for (int q = 0; q < 8; ++q) {
                    const float4 hv =
                        *reinterpret_cast<const float4*>(hrow + 4 * q); // broadcast
                    acc[b] += hv.x * Wreg[4 * q + 0];
                    acc[b] += hv.y * Wreg[4 * q + 1];
                    acc[b] += hv.z * Wreg[4 * q + 2];
                    acc[b] += hv.w * Wreg[4 * q + 3];
                }
            }
        }

        // ---- cross-slot K reduction through LDS ----
#pragma unroll
        for (int b = 0; b < BPG; ++b)
            pacc[b][col][slot] = acc[b];   // bank=(col+slot)%32: 2-way, free
        __syncthreads();

        if (tid < BPG * 32) {              // waves 0-1: 128 outputs
            const int b  = tid >> 5;
            // this thread's col == tid&31 == its own `col`; bias matches jcol
            float s = 0.f;
#pragma unroll
            for (int ss = 0; ss < NSLOT; ++ss) s += pacc[b][col][ss];
            const float hval = tanhf(s + bias);
            float* dst = out + (size_t)t * (BATCH * HID)
                             + (size_t)(g * BPG + b) * HID + jcol;
            st_agent(dst, hval);           // next step's h input
            if (t == SEQ - 1) {
                st_agent(out + (size_t)OUT_SEQ
                             + (size_t)(g * BPG + b) * HID + jcol, hval);
            }
        }
        __syncthreads();   // h stores drained (vmcnt(0)) before barrier count

        // ---- 32-wg group barrier (monotonic counter, agent scope) ----
        if (t < SEQ - 1) {
            if (tid == 0) {
                __threadfence();
                __hip_atomic_fetch_add(mycnt, 1u, __ATOMIC_ACQ_REL,
                                       __HIP_MEMORY_SCOPE_AGENT);
                const unsigned int target = 32u * (unsigned int)(t + 1);
                while (__hip_atomic_load(mycnt, __ATOMIC_ACQUIRE,
                                         __HIP_MEMORY_SCOPE_AGENT) < target) {
                    __builtin_amdgcn_s_sleep(2);
                }
                __threadfence();
            }
            __syncthreads();
        }
    }
}

extern "C" void kernel_launch(void* const* d_in, const int* in_sizes, int n_in,
                              void* d_out, int out_size, void* d_ws, size_t ws_size,
                              hipStream_t stream) {
    (void)in_sizes; (void)n_in; (void)out_size; (void)ws_size;
    const float* x  = (const float*)d_in[0];
    const float* V  = (const float*)d_in[1];
    const float* W  = (const float*)d_in[2];
    const float* b1 = (const float*)d_in[3];
    const float* b2 = (const float*)d_in[4];
    float* out = (float*)d_out;
    unsigned int* cnt = (unsigned int*)d_ws;

    // zero the per-group barrier counters (ws is poisoned 0xAA every launch)
    hipMemsetAsync(d_ws, 0, 1024, stream);

    hipLaunchKernelGGL(rnn_scan_kernel, dim3(512), dim3(1024), 0, stream,
                       x, V, W, b1, b2, out, cnt);
}

// Round 5
// 24178.465 us; speedup vs baseline: 1.8446x; 1.8446x over previous
//
#include <hip/hip_runtime.h>

// RNN scan: h_t = tanh(h_{t-1} @ W + x_t @ V + b + b2), 512 steps.
//
// Round-5 theory: rounds 1-4 show the allocator grants exactly HALF the
// per-wave register budget (req 128 -> 64, req 64 -> 32): the gfx9xx
// arch/accum file split. The W/V fragments therefore go in the UNUSED
// half — AGPRs — via the "a" asm constraint. Shape chosen so both halves
// fit at 16 waves/CU (4 waves/EU -> 64 arch + 64 accum):
//   grid 256 = 8 batch-groups (8 batches) x 32 col-chunks (32 cols),
//   1 wg/CU, 1024 threads (16 waves).
//   lane: col = lane&31, kh = lane>>5; slot = 2w+kh in [0,32)
//   Wreg[32] = W[32*slot .. +32)[jcol]   (32 AGPRs)
//   Vreg[8]  = V[8*slot  .. +8)[jcol]   (8 AGPRs)   => 40 <= 64 accum ✓
//   arch side: acc[8] + float4 temps + addrs ≈ 40   => <= 64 arch ✓
// Pins re-asserted every t-iteration so values cross the backedge in
// AGPRs (no remat, no copy-out, no spill).
//
// h is exchanged through d_out (chunk t of h_seq IS h_t) with agent-scope
// atomics; the 32 wgs sharing a batch-group sync via a monotonic counter.

#define SEQ    512
#define BATCH  64
#define INSZ   256
#define HID    1024
#define BPG    8     // batches per group
#define NSLOT  32    // k-slices (16 waves x 2 half-waves)
#define OUT_SEQ (SEQ * BATCH * HID)

__device__ __forceinline__ float ld_agent(const float* p) {
    return __hip_atomic_load(p, __ATOMIC_RELAXED, __HIP_MEMORY_SCOPE_AGENT);
}
__device__ __forceinline__ void st_agent(float* p, float v) {
    __hip_atomic_store(p, v, __ATOMIC_RELAXED, __HIP_MEMORY_SCOPE_AGENT);
}

__global__ void
__attribute__((amdgpu_flat_work_group_size(1024, 1024),
               amdgpu_waves_per_eu(4, 4)))
rnn_scan_kernel(
    const float* __restrict__ x,   // (SEQ, BATCH, INSZ)
    const float* __restrict__ V,   // (INSZ, HID)
    const float* __restrict__ W,   // (HID, HID)
    const float* __restrict__ b1,  // (HID,)
    const float* __restrict__ b2,  // (HID,)
    float* __restrict__ out,       // h_seq (SEQ*BATCH*HID) then h_last
    unsigned int* __restrict__ cnt)
{
    const int tid  = threadIdx.x;
    const int w    = tid >> 6;          // wave 0..15
    const int lane = tid & 63;
    const int col  = lane & 31;         // column within chunk
    const int kh   = lane >> 5;         // half-wave k split
    const int slot = w * 2 + kh;        // k-slice 0..31
    const int g    = blockIdx.x >> 5;   // batch group 0..7
    const int c    = blockIdx.x & 31;   // column chunk 0..31
    const int jcol = c * 32 + col;      // this lane's output column

    __shared__ __align__(16) float h_lds[BPG][HID];            // 32 KB
    __shared__ __align__(16) float pacc[BPG][32][NSLOT + 1];   // 33 KB

    // ---- persistent W/V fragments, placed in the ACCUM half (AGPRs) ----
    float Wreg[32];
#pragma unroll
    for (int i = 0; i < 32; ++i)
        Wreg[i] = W[(size_t)(slot * 32 + i) * HID + jcol];
    float Vreg[8];
#pragma unroll
    for (int i = 0; i < 8; ++i)
        Vreg[i] = V[(size_t)(slot * 8 + i) * HID + jcol];

#pragma unroll
    for (int i = 0; i < 32; ++i) asm volatile("" : "+a"(Wreg[i]));
#pragma unroll
    for (int i = 0; i < 8; ++i)  asm volatile("" : "+a"(Vreg[i]));

    const float bias = b1[jcol] + b2[jcol];
    unsigned int* mycnt = cnt + g * 16;   // 64B-padded per-group counter

    // loop-invariant bases
    const float* xg = x + (size_t)g * BPG * INSZ + slot * 8;
    const float* hg = out + (size_t)g * BPG * HID;

    for (int t = 0; t < SEQ; ++t) {
        // re-pin: values must cross the loop backedge in AGPRs
#pragma unroll
        for (int i = 0; i < 32; ++i) asm volatile("" : "+a"(Wreg[i]));
#pragma unroll
        for (int i = 0; i < 8; ++i)  asm volatile("" : "+a"(Vreg[i]));

        // ---- stage previous h (coherent: written by other CUs) ----
        if (t > 0) {
            const float* hprev = hg + (size_t)(t - 1) * (BATCH * HID);
#pragma unroll
            for (int i = 0; i < BPG; ++i)
                h_lds[i][tid] = ld_agent(hprev + i * HID + tid);
        }
        __syncthreads();

        float acc[BPG] = {0.f, 0.f, 0.f, 0.f, 0.f, 0.f, 0.f, 0.f};

        // ---- x_t @ V contribution (k-slice 8*slot .. +8) ----
        {
            const float* xt = xg + (size_t)t * (BATCH * INSZ);
#pragma unroll
            for (int q = 0; q < 2; ++q) {
                const float v0 = Vreg[4 * q + 0];
                const float v1 = Vreg[4 * q + 1];
                const float v2 = Vreg[4 * q + 2];
                const float v3 = Vreg[4 * q + 3];
#pragma unroll
                for (int b = 0; b < BPG; ++b) {
                    const float4 xa =
                        *reinterpret_cast<const float4*>(xt + b * INSZ + 4 * q);
                    acc[b] += xa.x * v0 + xa.y * v1 + xa.z * v2 + xa.w * v3;
                }
            }
        }

        // ---- h_{t-1} @ W contribution (k-slice 32*slot .. +32) ----
        if (t > 0) {
#pragma unroll
            for (int q = 0; q < 8; ++q) {
                const float w0 = Wreg[4 * q + 0];
                const float w1 = Wreg[4 * q + 1];
                const float w2 = Wreg[4 * q + 2];
                const float w3 = Wreg[4 * q + 3];
                const int   kk = slot * 32 + 4 * q;   // half-wave-uniform
#pragma unroll
                for (int b = 0; b < BPG; ++b) {
                    const float4 hv =
                        *reinterpret_cast<const float4*>(&h_lds[b][kk]);
                    acc[b] += hv.x * w0 + hv.y * w1 + hv.z * w2 + hv.w * w3;
                }
            }
        }

        // ---- cross-slot K reduction through LDS ----
#pragma unroll
        for (int b = 0; b < BPG; ++b)
            pacc[b][col][slot] = acc[b];   // bank=(col+slot)%32: 2-way, free
        __syncthreads();

        if (tid < BPG * 32) {              // waves 0-3: 256 outputs
            const int b = tid >> 5;        // batch within group
            // this thread's col == tid&31; its own jcol/bias match
            float s = 0.f;
#pragma unroll
            for (int ss = 0; ss < NSLOT; ++ss) s += pacc[b][col][ss];
            const float hval = tanhf(s + bias);
            float* dst = out + (size_t)t * (BATCH * HID)
                             + (size_t)(g * BPG + b) * HID + jcol;
            st_agent(dst, hval);           // next step's h input
            if (t == SEQ - 1) {
                st_agent(out + (size_t)OUT_SEQ
                             + (size_t)(g * BPG + b) * HID + jcol, hval);
            }
        }
        __syncthreads();   // h stores drained before barrier count

        // ---- 32-wg group barrier (monotonic counter, agent scope) ----
        if (t < SEQ - 1) {
            if (tid == 0) {
                __threadfence();
                __hip_atomic_fetch_add(mycnt, 1u, __ATOMIC_ACQ_REL,
                                       __HIP_MEMORY_SCOPE_AGENT);
                const unsigned int target = 32u * (unsigned int)(t + 1);
                while (__hip_atomic_load(mycnt, __ATOMIC_ACQUIRE,
                                         __HIP_MEMORY_SCOPE_AGENT) < target) {
                    __builtin_amdgcn_s_sleep(2);
                }
                __threadfence();
            }
            __syncthreads();
        }
    }
}

extern "C" void kernel_launch(void* const* d_in, const int* in_sizes, int n_in,
                              void* d_out, int out_size, void* d_ws, size_t ws_size,
                              hipStream_t stream) {
    (void)in_sizes; (void)n_in; (void)out_size; (void)ws_size;
    const float* x  = (const float*)d_in[0];
    const float* V  = (const float*)d_in[1];
    const float* W  = (const float*)d_in[2];
    const float* b1 = (const float*)d_in[3];
    const float* b2 = (const float*)d_in[4];
    float* out = (float*)d_out;
    unsigned int* cnt = (unsigned int*)d_ws;

    // zero the per-group barrier counters (ws is poisoned 0xAA every launch)
    hipMemsetAsync(d_ws, 0, 1024, stream);

    hipLaunchKernelGGL(rnn_scan_kernel, dim3(256), dim3(1024), 0, stream,
                       x, V, W, b1, b2, out, cnt);
}

// Round 6
// 12014.241 us; speedup vs baseline: 3.7122x; 2.0125x over previous
//
#include <hip/hip_runtime.h>

// RNN scan: h_t = tanh(h_{t-1} @ W + x_t @ V + b + b2), 512 steps.
//
// Round-6 pivot: five rounds of register-resident-W schemes all died to
// the allocator (grants half the budget; pins spill; re-pins re-spill —
// round 5: 20.6 GB of spill WRITES). New design has NO allocator
// dependence: W lives in LDS. Worst-case pressure re-reads LDS, not HBM.
//
// Kernel 1 (xv_kernel): xv = x@V + b1 + b2 written INTO d_out (slot t of
// h_seq IS xv_t until the scan overwrites it with h_t; the overwriting
// thread reads xv before writing h — no extra workspace).
// Kernel 2 (scan_kernel): persistent, 256 wgs x 1024 thr, 1 wg/CU
// (forced by 148 KB LDS), 4 batch-groups (16 batches) x 64 col-chunks
// (16 cols). Thread (c=tid&15, ks=tid>>4): 16-k slice x 16 batches from
// LDS. W frag 4x ds_read_b128 (pad 1028: ~2-way banks); h reads are
// 4-address broadcasts (free). Cross-ks reduce: shfl_xor(16,32) +
// 16-wave pacc (pad 20: 2-way) + 256 reducer threads (+xv, tanh, store).
// h exchanged through d_out with agent-scope atomics (bypass stale L2);
// 64-wg groups sync on a monotonic counter in d_ws.

#define SEQ    512
#define BATCH  64
#define INSZ   256
#define HID    1024
#define HB     (BATCH * HID)          // 65536
#define OUT_SEQ (SEQ * HB)
#define BPG    16                      // batches per scan group
#define CPW    16                      // cols per wg
#define NWG_PER_GRP 64

__device__ __forceinline__ float ld_agent(const float* p) {
    return __hip_atomic_load(p, __ATOMIC_RELAXED, __HIP_MEMORY_SCOPE_AGENT);
}
__device__ __forceinline__ void st_agent(float* p, float v) {
    __hip_atomic_store(p, v, __ATOMIC_RELAXED, __HIP_MEMORY_SCOPE_AGENT);
}

// ---------------- Kernel 1: xv = x @ V + b1 + b2  (into out) ----------------
// 2048 wgs x 1024 thr; wg handles 16 consecutive (t,b) rows, thread = col.
__global__ void __launch_bounds__(1024)
xv_kernel(const float* __restrict__ x, const float* __restrict__ V,
          const float* __restrict__ b1, const float* __restrict__ b2,
          float* __restrict__ out)
{
    const int tid  = threadIdx.x;          // output column j
    const int row0 = blockIdx.x * 16;      // row = t*BATCH + b
    __shared__ __align__(16) float x_lds[16 * INSZ];   // 16 KB

    // stage 16 x-rows (4096 floats = 1024 float4, one per thread)
    reinterpret_cast<float4*>(x_lds)[tid] =
        reinterpret_cast<const float4*>(x + (size_t)row0 * INSZ)[tid];
    __syncthreads();

    float acc[16];
#pragma unroll
    for (int r = 0; r < 16; ++r) acc[r] = 0.f;

    for (int k = 0; k < INSZ; k += 4) {    // V reads coalesced, L2-resident
        const float v0 = V[(size_t)(k + 0) * HID + tid];
        const float v1 = V[(size_t)(k + 1) * HID + tid];
        const float v2 = V[(size_t)(k + 2) * HID + tid];
        const float v3 = V[(size_t)(k + 3) * HID + tid];
#pragma unroll
        for (int r = 0; r < 16; ++r) {     // x_lds reads: uniform = broadcast
            acc[r] += x_lds[r * INSZ + k    ] * v0;
            acc[r] += x_lds[r * INSZ + k + 1] * v1;
            acc[r] += x_lds[r * INSZ + k + 2] * v2;
            acc[r] += x_lds[r * INSZ + k + 3] * v3;
        }
    }
    const float bias = b1[tid] + b2[tid];
    float* dst = out + (size_t)row0 * HID + tid;
#pragma unroll
    for (int r = 0; r < 16; ++r)
        dst[(size_t)r * HID] = acc[r] + bias;
}

// ---------------- Kernel 2: the scan ----------------
__global__ void __launch_bounds__(1024)
scan_kernel(const float* __restrict__ W, float* __restrict__ out,
            unsigned int* __restrict__ cnt)
{
    const int tid  = threadIdx.x;
    const int w    = tid >> 6;        // wave 0..15
    const int lane = tid & 63;
    const int c    = tid & 15;        // col within chunk
    const int ks   = tid >> 4;        // k-slice 0..63 (16 k each)
    const int bg   = blockIdx.x >> 6; // batch group 0..3
    const int cc   = blockIdx.x & 63; // col chunk 0..63
    const int jcol = cc * CPW + c;

    __shared__ __align__(16) float W_lds[16][1028];   // 65792 B, ~2-way banks
    __shared__ __align__(16) float h_lds[16][1024];   // 65536 B
    __shared__ __align__(16) float pacc[16][16][20];  // 20480 B, 2-way banks

    const int kb = ks * 16;

    // one-time W slice load: W_lds[c][k] = W[k][jcol]
#pragma unroll
    for (int i = 0; i < 16; ++i)
        W_lds[c][kb + i] = W[(size_t)(kb + i) * HID + jcol];
    __syncthreads();

    unsigned int* mycnt = cnt + bg * 16;   // 64B-padded per-group counter

    for (int t = 0; t < SEQ; ++t) {
        // prefetch this step's xv tile (only OUR wg ever writes these addrs;
        // plain load is safe: region untouched since the pre-pass)
        float xval = 0.f;
        if (tid < 256)
            xval = out[(size_t)t * HB
                       + (size_t)(bg * BPG + (tid >> 4)) * HID
                       + cc * CPW + (tid & 15)];

        // stage previous h (agent loads bypass possibly-stale local L2)
        if (t > 0) {
            const float* hprev = out + (size_t)(t - 1) * HB
                                     + (size_t)bg * BPG * HID;
#pragma unroll
            for (int i = 0; i < BPG; ++i)
                h_lds[i][tid] = ld_agent(hprev + (size_t)i * HID + tid);
        }
        __syncthreads();

        // W fragment for this (c, ks): 16 floats, re-read from LDS each step
        const float4 wf0 = *reinterpret_cast<const float4*>(&W_lds[c][kb]);
        const float4 wf1 = *reinterpret_cast<const float4*>(&W_lds[c][kb + 4]);
        const float4 wf2 = *reinterpret_cast<const float4*>(&W_lds[c][kb + 8]);
        const float4 wf3 = *reinterpret_cast<const float4*>(&W_lds[c][kb + 12]);

#pragma unroll
        for (int half = 0; half < 2; ++half) {   // 8 batches at a time: low VGPR
            float acc[8];
#pragma unroll
            for (int i = 0; i < 8; ++i) acc[i] = 0.f;
            if (t > 0) {
#pragma unroll
                for (int b8 = 0; b8 < 8; ++b8) {
                    const float* hrow = &h_lds[half * 8 + b8][kb]; // broadcast
                    const float4 h0 = reinterpret_cast<const float4*>(hrow)[0];
                    const float4 h1 = reinterpret_cast<const float4*>(hrow)[1];
                    const float4 h2 = reinterpret_cast<const float4*>(hrow)[2];
                    const float4 h3 = reinterpret_cast<const float4*>(hrow)[3];
                    acc[b8] += h0.x*wf0.x + h0.y*wf0.y + h0.z*wf0.z + h0.w*wf0.w
                             + h1.x*wf1.x + h1.y*wf1.y + h1.z*wf1.z + h1.w*wf1.w
                             + h2.x*wf2.x + h2.y*wf2.y + h2.z*wf2.z + h2.w*wf2.w
                             + h3.x*wf3.x + h3.y*wf3.y + h3.z*wf3.z + h3.w*wf3.w;
                }
            }
            // reduce across the wave's 4 k-slices (lanes 16 apart share c)
#pragma unroll
            for (int i = 0; i < 8; ++i) {
                acc[i] += __shfl_xor(acc[i], 16, 64);
                acc[i] += __shfl_xor(acc[i], 32, 64);
            }
            if (lane < 16) {   // lane == c
                *reinterpret_cast<float4*>(&pacc[w][lane][half * 8]) =
                    make_float4(acc[0], acc[1], acc[2], acc[3]);
                *reinterpret_cast<float4*>(&pacc[w][lane][half * 8 + 4]) =
                    make_float4(acc[4], acc[5], acc[6], acc[7]);
            }
        }
        __syncthreads();

        // final reduce over 16 waves + tanh + store (h_t overwrites xv_t)
        if (tid < 256) {
            const int b  = tid >> 4;
            const int c2 = tid & 15;
            float s = xval;
#pragma unroll
            for (int w2 = 0; w2 < 16; ++w2) s += pacc[w2][c2][b];
            const float hval = tanhf(s);
            float* dst = out + (size_t)t * HB
                             + (size_t)(bg * BPG + b) * HID + cc * CPW + c2;
            st_agent(dst, hval);
            if (t == SEQ - 1)
                st_agent(out + (size_t)OUT_SEQ
                             + (size_t)(bg * BPG + b) * HID + cc * CPW + c2,
                         hval);
        }
        __syncthreads();   // stores drained (vmcnt(0)) before barrier count

        // 64-wg group barrier (monotonic counter, agent scope)
        if (t < SEQ - 1) {
            if (tid == 0) {
                __threadfence();
                __hip_atomic_fetch_add(mycnt, 1u, __ATOMIC_ACQ_REL,
                                       __HIP_MEMORY_SCOPE_AGENT);
                const unsigned int target =
                    (unsigned int)NWG_PER_GRP * (unsigned int)(t + 1);
                while (__hip_atomic_load(mycnt, __ATOMIC_ACQUIRE,
                                         __HIP_MEMORY_SCOPE_AGENT) < target) {
                    __builtin_amdgcn_s_sleep(2);
                }
                __threadfence();
            }
            __syncthreads();
        }
    }
}

extern "C" void kernel_launch(void* const* d_in, const int* in_sizes, int n_in,
                              void* d_out, int out_size, void* d_ws, size_t ws_size,
                              hipStream_t stream) {
    (void)in_sizes; (void)n_in; (void)out_size; (void)ws_size;
    const float* x  = (const float*)d_in[0];
    const float* V  = (const float*)d_in[1];
    const float* W  = (const float*)d_in[2];
    const float* b1 = (const float*)d_in[3];
    const float* b2 = (const float*)d_in[4];
    float* out = (float*)d_out;
    unsigned int* cnt = (unsigned int*)d_ws;

    // zero the per-group barrier counters (ws is poisoned 0xAA every launch)
    hipMemsetAsync(d_ws, 0, 1024, stream);

    // pre-pass: xv into out (kernel boundary makes it visible to the scan)
    hipLaunchKernelGGL(xv_kernel, dim3(SEQ * BATCH / 16), dim3(1024), 0, stream,
                       x, V, b1, b2, out);

    // persistent scan: 256 wgs, 1 wg/CU (LDS-forced), all co-resident
    hipLaunchKernelGGL(scan_kernel, dim3(256), dim3(1024), 0, stream,
                       W, out, cnt);
}